// Round 11
// baseline (166.127 us; speedup 1.0000x reference)
//
#include <hip/hip_runtime.h>
#include <hip/hip_bf16.h>

#define NPIX (1 << 20)
#define HDIM 1024
#define NREG 64          // regions: img*8 + (tile&7)
#define REGCAP 4096      // slots per region
#define TAILBLK 256      // tail_k grid: 1 block/CU, co-resident by construction

#define WBAR() __builtin_amdgcn_wave_barrier()

// ============ slot-level union-find (global, union-by-min) ============
__device__ __forceinline__ int find_f(int* F, int x) {
    for (;;) {
        int p = F[x];
        if (p == x) return x;
        int gp = F[p];
        if (gp == p) return p;
        F[x] = gp;   // path halving, benign race
        x = gp;
    }
}
__device__ __forceinline__ void unite_f(int* F, int a, int b) {
    a = find_f(F, a); b = find_f(F, b);
    while (a != b) {
        if (a < b) { int t = a; a = b; b = t; }
        int old = atomicCAS(&F[a], a, b);
        if (old == a) return;
        a = find_f(F, old); b = find_f(F, b);
    }
}

// ============ LDS union-find over run nodes (id = row*16 + k) ============
__device__ __forceinline__ int find_r(int* R, int n) {
    int p = R[n];
    while (p != n) {
        int gp = R[p];
        if (gp == p) return p;
        R[n] = gp;
        n = gp;
        p = R[n];
    }
    return n;
}
__device__ __forceinline__ void unite_r(int* R, int a, int b) {
    a = find_r(R, a); b = find_r(R, b);
    while (a != b) {
        if (a < b) { int t = a; a = b; b = t; }
        int old = atomicCAS(&R[a], a, b);
        if (old == a) return;
        a = find_r(R, old); b = find_r(R, b);
    }
}

// ============ phase A: 4 tiles/block, one tile per WAVE, interleaved ======
__global__ __launch_bounds__(256) void local_k(
        const float4* __restrict__ pred4, const float4* __restrict__ targ4,
        int* __restrict__ edges, int* __restrict__ F,
        float2* __restrict__ fragSums,
        int* __restrict__ fragCnt, int nwg) {
    int wid = threadIdx.x >> 6;
    int l   = threadIdx.x & 63;
    int tile = wid * nwg + blockIdx.x;     // interleaved: block mixes 4 distant tiles
    int img = tile >> 10;
    int ty = (tile >> 5) & 31, tx = tile & 31;
    int r = l >> 1, h = l & 1;

    __shared__ int s_ruf[4][512];
    __shared__ float s_i[4][512], s_u[4][512];
    int*   ruf = &s_ruf[wid][0];
    float* si  = &s_i[wid][0];
    float* su  = &s_u[wid][0];

    int rowg = img * HDIM + ty * 32 + r;
    int qb = rowg * 256 + tx * 8 + h * 4;
    int ebase = tile * 128;

    float sv[16], iv[16];
    unsigned hm = 0;
    #pragma unroll
    for (int q = 0; q < 4; ++q) {
        float4 P4 = pred4[qb + q];
        float4 T4 = targ4[qb + q];
        float s0 = P4.x + T4.x, s1 = P4.y + T4.y, s2 = P4.z + T4.z, s3 = P4.w + T4.w;
        sv[q*4+0] = s0; sv[q*4+1] = s1; sv[q*4+2] = s2; sv[q*4+3] = s3;
        iv[q*4+0] = P4.x * T4.x; iv[q*4+1] = P4.y * T4.y;
        iv[q*4+2] = P4.z * T4.z; iv[q*4+3] = P4.w * T4.w;
        if (s0 > 0.f) hm |= 1u << (q*4+0);
        if (s1 > 0.f) hm |= 1u << (q*4+1);
        if (s2 > 0.f) hm |= 1u << (q*4+2);
        if (s3 > 0.f) hm |= 1u << (q*4+3);
    }
    unsigned m = hm << (h * 16);
    m |= __shfl_xor(m, 1);                 // full 32-bit row mask on both lanes
    unsigned st = m & ~(m << 1);           // run starts
    int nrun = __popc(st);

    if (__ballot(m != 0) == 0ull) {        // empty tile: -1 edges, 2 stores/lane
        edges[ebase + l] = -1;             // L(0..31) | R(32..63)
        edges[ebase + 64 + l] = -1;        // T(64..95) | B(96..127)
        return;
    }

    #pragma unroll
    for (int k = 0; k < 8; ++k) ruf[l * 8 + k] = l * 8 + k;

    // ---- P3a: per-run sums; straddler partial passed in registers ----
    int nrun0 = __popc(st & 0xFFFFu);
    bool strad = ((m >> 15) & 1) && ((m >> 16) & 1);
    float ai = 0.f, au = 0.f, fi = 0.f, fu = 0.f;
    int rid = h ? (nrun0 - 1) : -1;
    bool in = false;
    #pragma unroll
    for (int j = 0; j < 16; ++j) {
        if ((hm >> j) & 1) {
            int x = h * 16 + j;
            if ((st >> x) & 1) {
                if (in) { si[r*16+rid] = ai; su[r*16+rid] = au; }
                ++rid; ai = 0.f; au = 0.f; in = true;
            }
            if (in) { ai += iv[j]; au += sv[j]; }
            else    { fi += iv[j]; fu += sv[j]; }   // leading continuation (h=1)
        }
    }
    float gi = __shfl_xor(fi, 1), gu = __shfl_xor(fu, 1);
    if (in) {
        if (h == 0 && strad) { ai += gi; au += gu; }
        si[r*16+rid] = ai; su[r*16+rid] = au;
    }
    WBAR();
    // ---- P4: vertical run unions, lane pair per row boundary ----
    {
        int bsrc = (l & ~1) + 2; if (bsrc > 63) bsrc = 63;
        unsigned mb = __shfl(m, bsrc);
        if (l < 62) {
            unsigned stb = mb & ~(mb << 1);
            unsigned o = m & mb;
            unsigned os = o & ~(o << 1);
            os &= h ? 0xFFFF0000u : 0x0000FFFFu;
            while (os) {
                int x = __ffs(os) - 1; os &= os - 1;
                unsigned below = (2u << x) - 1;
                unite_r(ruf, r * 16 + __popc(st & below) - 1,
                             (r + 1) * 16 + __popc(stb & below) - 1);
            }
        }
    }
    WBAR();
    // ---- P5a: parallel pointer-doubling flatten (all 8 nodes per round) ----
    for (int it = 0; it < 10; ++it) {
        bool ch = false;
        #pragma unroll
        for (int k = 0; k < 8; ++k) {
            int n = l * 8 + k;
            int p = ruf[n];
            int gp = ruf[p];
            if (p != gp) { ruf[n] = gp; ch = true; }
        }
        if (!__any(ch)) break;
    }
    WBAR();
    // ---- P5b: fold donor run sums into roots (depth<=1 now) ----
    #pragma unroll
    for (int k = 0; k < 8; ++k) {
        int n = l * 8 + k;                 // nodes of own row (r = l>>1)
        if ((n & 15) < nrun) {
            int root = ruf[n];
            if (root != n) {
                atomicAdd(&si[root], si[n]);
                atomicAdd(&su[root], su[n]);
            }
        }
    }
    WBAR();
    // ---- P7: slot alloc; ballot-based rank (no shuffle chain) ----
    {
        bool isroot[8];
        #pragma unroll
        for (int k = 0; k < 8; ++k) {
            int n = l * 8 + k;
            isroot[k] = ((n & 15) < nrun) && (ruf[n] == n);
        }
        unsigned long long lt = (1ull << l) - 1;
        int tot = 0; int myoff[8];
        #pragma unroll
        for (int k = 0; k < 8; ++k) {
            unsigned long long b = __ballot(isroot[k]);
            myoff[k] = tot + __popcll(b & lt);
            tot += __popcll(b);
        }
        int cidx = (img << 3) | (tile & 7);
        int base = 0;
        if (l == 0) base = atomicAdd(&fragCnt[cidx], tot);
        base = __shfl(base, 0);
        #pragma unroll
        for (int k = 0; k < 8; ++k) {
            if (isroot[k]) {
                int n = l * 8 + k;
                int off = base + myoff[k];
                if (off < REGCAP) {
                    int slot = cidx * REGCAP + off;
                    F[slot] = slot;
                    fragSums[slot] = make_float2(si[n], su[n]);
                    ruf[n] = ~slot;
                } else ruf[n] = ~0;
            }
        }
    }
    WBAR();
    // ---- edges: L/R by row-pair, T/B one pixel per lane ----
    {
        int s = -1;
        if (h == 0) {
            if (m & 1u) { int v = ruf[r * 16]; s = (v < 0) ? ~v : ~ruf[v]; }
            edges[ebase + r] = s;
        } else {
            if (m >> 31) { int v = ruf[r * 16 + nrun - 1]; s = (v < 0) ? ~v : ~ruf[v]; }
            edges[ebase + 32 + r] = s;
        }
    }
    {
        int srcl = (l < 32) ? 0 : 62;      // lane holding full mask of row 0 / 31
        unsigned mm = __shfl(m, srcl);
        int x = l & 31;
        int s = -1;
        if ((mm >> x) & 1) {
            unsigned stt = mm & ~(mm << 1);
            int row = (l < 32) ? 0 : 31;
            int node = row * 16 + __popc(stt & ((2u << x) - 1)) - 1;
            int v = ruf[node];
            s = (v < 0) ? ~v : ~ruf[v];
        }
        edges[ebase + 64 + l] = s;
    }
}

// ============ software grid barrier (all TAILBLK blocks co-resident) ======
__device__ __forceinline__ void gridbar(int* bar, int target) {
    __syncthreads();
    if (threadIdx.x == 0) {
        __threadfence();                       // release prior writes
        atomicAdd(bar, 1);
        while (atomicAdd(bar, 0) < target)     // device-scope load (L2)
            __builtin_amdgcn_s_sleep(8);
        __threadfence();                       // acquire (invalidate L1)
    }
    __syncthreads();
}

// ============ fused tail: bound -> merge -> dice -> final ============
__global__ __launch_bounds__(256) void tail_k(
        const int* __restrict__ edges, int* __restrict__ F,
        float* __restrict__ fragSums, const int* __restrict__ fragCnt,
        float* __restrict__ partials, int* __restrict__ bar,
        float* __restrict__ out, int b0, int C, int B, int doFinal) {
    const int nblk = gridDim.x;
    // ---- phase 1: boundary slot unions ----
    int nE = C * 63488;
    for (int e = blockIdx.x * 256 + threadIdx.x; e < nE; e += nblk * 256) {
        int img = e / 63488, e2 = e % 63488;
        int sA, sB;
        if (e2 < 31744) {          // vertical: tx=k <-> k+1, row y
            int k = e2 >> 10, y = e2 & 1023;
            int tileA = img * 1024 + (y >> 5) * 32 + k;
            sA = edges[tileA * 128 + 32 + (y & 31)];
            sB = edges[(tileA + 1) * 128 + (y & 31)];
        } else {                   // horizontal
            int e3 = e2 - 31744;
            int k = e3 >> 10, x = e3 & 1023;
            int tileA = img * 1024 + k * 32 + (x >> 5);
            sA = edges[tileA * 128 + 96 + (x & 31)];
            sB = edges[(tileA + 32) * 128 + 64 + (x & 31)];
        }
        if (sA >= 0 && sB >= 0) unite_f(F, sA, sB);
    }
    gridbar(bar, nblk);
    // ---- phase 2: fold donor fragments into final roots ----
    int total = C * 8 * REGCAP;
    for (int i = blockIdx.x * 256 + threadIdx.x; i < total; i += nblk * 256) {
        int cidx = i >> 12, off = i & (REGCAP - 1);
        int cnt = fragCnt[cidx]; if (cnt > REGCAP) cnt = REGCAP;
        if (off >= cnt) continue;
        int rt = find_f(F, i);
        if (rt != i) {
            float2 d = ((const float2*)fragSums)[i];
            unsafeAtomicAdd(&fragSums[2 * rt], d.x);
            unsafeAtomicAdd(&fragSums[2 * rt + 1], d.y);
        }
    }
    gridbar(bar, 2 * nblk);
    // ---- phase 3: dice per region (block = region), WRITE partials ----
    if (blockIdx.x < C * 8) {
        int cidx = blockIdx.x;
        int cnt = fragCnt[cidx]; if (cnt > REGCAP) cnt = REGCAP;
        float ds = 0.f, dn = 0.f;
        for (int off = threadIdx.x; off < cnt; off += 256) {
            int i = cidx * REGCAP + off;
            if (F[i] != i) continue;
            float2 s2 = ((const float2*)fragSums)[i];
            ds += (2.f * s2.x + 1e-6f) / (s2.y + 1e-6f);
            dn += 1.f;
        }
        #pragma unroll
        for (int d = 32; d > 0; d >>= 1) {
            ds += __shfl_down(ds, d);
            dn += __shfl_down(dn, d);
        }
        __shared__ float s_s[4], s_n[4];
        int wv = threadIdx.x >> 6;
        if ((threadIdx.x & 63) == 0) { s_s[wv] = ds; s_n[wv] = dn; }
        __syncthreads();
        if (threadIdx.x == 0) {
            int img = b0 + (cidx >> 3), sub = cidx & 7;
            partials[img * 16 + sub * 2]     = s_s[0] + s_s[1] + s_s[2] + s_s[3];
            partials[img * 16 + sub * 2 + 1] = s_n[0] + s_n[1] + s_n[2] + s_n[3];
        }
    }
    if (!doFinal) return;
    gridbar(bar, 3 * nblk);
    // ---- phase 4: final mean ----
    if (blockIdx.x == 0 && threadIdx.x == 0) {
        float acc = 0.f;
        for (int img = 0; img < B; ++img) {
            float s = 0.f, n = 0.f;
            for (int sub = 0; sub < 8; ++sub) {
                s += partials[img * 16 + sub * 2];
                n += partials[img * 16 + sub * 2 + 1];
            }
            acc += (n > 0.f) ? (1.f - s / n) : 1.f;
        }
        out[0] = acc / (float)B;
    }
}

__global__ void zero_k(int* __restrict__ fragCnt, int* __restrict__ bar) {
    int i = threadIdx.x;
    if (i < NREG) fragCnt[i] = 0;
    if (i == NREG) bar[0] = 0;
}

// ============ launch ============
extern "C" void kernel_launch(void* const* d_in, const int* in_sizes, int n_in,
                              void* d_out, int out_size, void* d_ws, size_t ws_size,
                              hipStream_t stream) {
    const float* pred = (const float*)d_in[0];
    const float* targ = (const float*)d_in[1];
    float* out = (float*)d_out;
    int B = in_sizes[0] / NPIX;
    if (B < 1) B = 1;

    char* ws = (char*)d_ws;
    size_t off = 0;
    float* partials = (float*)ws;                       // B*16 floats
    off += ((size_t)B * 16 * sizeof(float) + 255) & ~(size_t)255;
    int* fragCnt = (int*)(ws + off);
    off += ((size_t)NREG * 4 + 255) & ~(size_t)255;
    int* bar = (int*)(ws + off);
    off += 256;

    // fixed slot pool: F 1MB + fragSums 2MB
    const size_t NSLOT = (size_t)NREG * REGCAP;
    int*    F        = (int*)   (ws + off); off += NSLOT * 4;
    float2* fragSums = (float2*)(ws + off); off += NSLOT * 8;
    size_t fixed = off;

    const size_t perImg = (size_t)1024 * 128 * 4;       // edges only (512KB)
    int maxC = 1;
    if (ws_size > fixed + perImg) {
        size_t mm = (ws_size - fixed) / perImg;
        maxC = (int)(mm < (size_t)B ? mm : (size_t)B);
        if (maxC < 1) maxC = 1;
        if (maxC > 8) maxC = 8;
    }
    int* edgesA = (int*)(ws + off);

    for (int b0 = 0; b0 < B; b0 += maxC) {
        int C = (B - b0 < maxC) ? (B - b0) : maxC;
        const float* pc = pred + (size_t)b0 * NPIX;
        const float* tc = targ + (size_t)b0 * NPIX;
        int nwg = C * 256;
        int doFinal = (b0 + C >= B) ? 1 : 0;
        zero_k<<<1, 128, 0, stream>>>(fragCnt, bar);
        local_k<<<nwg, 256, 0, stream>>>((const float4*)pc, (const float4*)tc,
                                         edgesA, F, fragSums, fragCnt, nwg);
        tail_k<<<TAILBLK, 256, 0, stream>>>(edgesA, F, (float*)fragSums, fragCnt,
                                            partials, bar, out, b0, C, B, doFinal);
    }
}

// Round 12
// 112.489 us; speedup vs baseline: 1.4768x; 1.4768x over previous
//
#include <hip/hip_runtime.h>
#include <hip/hip_bf16.h>

#define NPIX (1 << 20)
#define HDIM 1024
#define NREG 64          // regions: img*8 + (tile&7)
#define REGCAP 4096      // slots per region

#define WBAR() __builtin_amdgcn_wave_barrier()

// ============ slot-level union-find (global, union-by-min) ============
__device__ __forceinline__ int find_f(int* F, int x) {
    for (;;) {
        int p = F[x];
        if (p == x) return x;
        int gp = F[p];
        if (gp == p) return p;
        F[x] = gp;   // path halving, benign race
        x = gp;
    }
}
__device__ __forceinline__ void unite_f(int* F, int a, int b) {
    a = find_f(F, a); b = find_f(F, b);
    while (a != b) {
        if (a < b) { int t = a; a = b; b = t; }
        int old = atomicCAS(&F[a], a, b);
        if (old == a) return;
        a = find_f(F, old); b = find_f(F, b);
    }
}

// ============ LDS union-find over run nodes (id = row*16 + k) ============
__device__ __forceinline__ int find_r(int* R, int n) {
    int p = R[n];
    while (p != n) {
        int gp = R[p];
        if (gp == p) return p;
        R[n] = gp;
        n = gp;
        p = R[n];
    }
    return n;
}
__device__ __forceinline__ void unite_r(int* R, int a, int b) {
    a = find_r(R, a); b = find_r(R, b);
    while (a != b) {
        if (a < b) { int t = a; a = b; b = t; }
        int old = atomicCAS(&R[a], a, b);
        if (old == a) return;
        a = find_r(R, old); b = find_r(R, b);
    }
}

// ============ phase A: 4 tiles/block, one tile per WAVE, interleaved ======
__global__ __launch_bounds__(256) void local_k(
        const float4* __restrict__ pred4, const float4* __restrict__ targ4,
        int* __restrict__ edges, int* __restrict__ F,
        float2* __restrict__ fragSums,
        int* __restrict__ fragCnt, int nwg) {
    int wid = threadIdx.x >> 6;
    int l   = threadIdx.x & 63;
    int tile = wid * nwg + blockIdx.x;     // interleaved: block mixes 4 distant tiles
    int img = tile >> 10;
    int ty = (tile >> 5) & 31, tx = tile & 31;
    int r = l >> 1, h = l & 1;

    __shared__ int s_ruf[4][512];
    __shared__ float s_i[4][512], s_u[4][512];
    int*   ruf = &s_ruf[wid][0];
    float* si  = &s_i[wid][0];
    float* su  = &s_u[wid][0];

    int rowg = img * HDIM + ty * 32 + r;
    int qb = rowg * 256 + tx * 8 + h * 4;
    int ebase = tile * 128;

    float sv[16], iv[16];
    unsigned hm = 0;
    #pragma unroll
    for (int q = 0; q < 4; ++q) {
        float4 P4 = pred4[qb + q];
        float4 T4 = targ4[qb + q];
        float s0 = P4.x + T4.x, s1 = P4.y + T4.y, s2 = P4.z + T4.z, s3 = P4.w + T4.w;
        sv[q*4+0] = s0; sv[q*4+1] = s1; sv[q*4+2] = s2; sv[q*4+3] = s3;
        iv[q*4+0] = P4.x * T4.x; iv[q*4+1] = P4.y * T4.y;
        iv[q*4+2] = P4.z * T4.z; iv[q*4+3] = P4.w * T4.w;
        if (s0 > 0.f) hm |= 1u << (q*4+0);
        if (s1 > 0.f) hm |= 1u << (q*4+1);
        if (s2 > 0.f) hm |= 1u << (q*4+2);
        if (s3 > 0.f) hm |= 1u << (q*4+3);
    }
    unsigned m = hm << (h * 16);
    m |= __shfl_xor(m, 1);                 // full 32-bit row mask on both lanes
    unsigned st = m & ~(m << 1);           // run starts
    int nrun = __popc(st);

    if (__ballot(m != 0) == 0ull) {        // empty tile: -1 edges, 2 stores/lane
        edges[ebase + l] = -1;             // L(0..31) | R(32..63)
        edges[ebase + 64 + l] = -1;        // T(64..95) | B(96..127)
        return;
    }

    #pragma unroll
    for (int k = 0; k < 8; ++k) ruf[l * 8 + k] = l * 8 + k;

    // ---- P3a: per-run sums; straddler partial passed in registers ----
    int nrun0 = __popc(st & 0xFFFFu);
    bool strad = ((m >> 15) & 1) && ((m >> 16) & 1);
    float ai = 0.f, au = 0.f, fi = 0.f, fu = 0.f;
    int rid = h ? (nrun0 - 1) : -1;
    bool in = false;
    #pragma unroll
    for (int j = 0; j < 16; ++j) {
        if ((hm >> j) & 1) {
            int x = h * 16 + j;
            if ((st >> x) & 1) {
                if (in) { si[r*16+rid] = ai; su[r*16+rid] = au; }
                ++rid; ai = 0.f; au = 0.f; in = true;
            }
            if (in) { ai += iv[j]; au += sv[j]; }
            else    { fi += iv[j]; fu += sv[j]; }   // leading continuation (h=1)
        }
    }
    float gi = __shfl_xor(fi, 1), gu = __shfl_xor(fu, 1);
    if (in) {
        if (h == 0 && strad) { ai += gi; au += gu; }
        si[r*16+rid] = ai; su[r*16+rid] = au;
    }
    WBAR();
    // ---- P4: vertical run unions, lane pair per row boundary ----
    {
        int bsrc = (l & ~1) + 2; if (bsrc > 63) bsrc = 63;
        unsigned mb = __shfl(m, bsrc);
        if (l < 62) {
            unsigned stb = mb & ~(mb << 1);
            unsigned o = m & mb;
            unsigned os = o & ~(o << 1);
            os &= h ? 0xFFFF0000u : 0x0000FFFFu;
            while (os) {
                int x = __ffs(os) - 1; os &= os - 1;
                unsigned below = (2u << x) - 1;
                unite_r(ruf, r * 16 + __popc(st & below) - 1,
                             (r + 1) * 16 + __popc(stb & below) - 1);
            }
        }
    }
    WBAR();
    // ---- P5a: parallel pointer-doubling flatten (all 8 nodes per round) ----
    for (int it = 0; it < 10; ++it) {
        bool ch = false;
        #pragma unroll
        for (int k = 0; k < 8; ++k) {
            int n = l * 8 + k;
            int p = ruf[n];
            int gp = ruf[p];
            if (p != gp) { ruf[n] = gp; ch = true; }
        }
        if (!__any(ch)) break;
    }
    WBAR();
    // ---- P5b: fold donor run sums into roots (depth<=1 now) ----
    #pragma unroll
    for (int k = 0; k < 8; ++k) {
        int n = l * 8 + k;                 // nodes of own row (r = l>>1)
        if ((n & 15) < nrun) {
            int root = ruf[n];
            if (root != n) {
                atomicAdd(&si[root], si[n]);
                atomicAdd(&su[root], su[n]);
            }
        }
    }
    WBAR();
    // ---- P7: slot alloc; ballot-based rank (no shuffle chain) ----
    {
        bool isroot[8];
        #pragma unroll
        for (int k = 0; k < 8; ++k) {
            int n = l * 8 + k;
            isroot[k] = ((n & 15) < nrun) && (ruf[n] == n);
        }
        unsigned long long lt = (1ull << l) - 1;
        int tot = 0; int myoff[8];
        #pragma unroll
        for (int k = 0; k < 8; ++k) {
            unsigned long long b = __ballot(isroot[k]);
            myoff[k] = tot + __popcll(b & lt);
            tot += __popcll(b);
        }
        int cidx = (img << 3) | (tile & 7);
        int base = 0;
        if (l == 0) base = atomicAdd(&fragCnt[cidx], tot);
        base = __shfl(base, 0);
        #pragma unroll
        for (int k = 0; k < 8; ++k) {
            if (isroot[k]) {
                int n = l * 8 + k;
                int off = base + myoff[k];
                if (off < REGCAP) {
                    int slot = cidx * REGCAP + off;
                    F[slot] = slot;
                    fragSums[slot] = make_float2(si[n], su[n]);
                    ruf[n] = ~slot;
                } else ruf[n] = ~0;
            }
        }
    }
    WBAR();
    // ---- edges: L/R by row-pair, T/B one pixel per lane ----
    {
        int s = -1;
        if (h == 0) {
            if (m & 1u) { int v = ruf[r * 16]; s = (v < 0) ? ~v : ~ruf[v]; }
            edges[ebase + r] = s;
        } else {
            if (m >> 31) { int v = ruf[r * 16 + nrun - 1]; s = (v < 0) ? ~v : ~ruf[v]; }
            edges[ebase + 32 + r] = s;
        }
    }
    {
        int srcl = (l < 32) ? 0 : 62;      // lane holding full mask of row 0 / 31
        unsigned mm = __shfl(m, srcl);
        int x = l & 31;
        int s = -1;
        if ((mm >> x) & 1) {
            unsigned stt = mm & ~(mm << 1);
            int row = (l < 32) ? 0 : 31;
            int node = row * 16 + __popc(stt & ((2u << x) - 1)) - 1;
            int v = ruf[node];
            s = (v < 0) ? ~v : ~ruf[v];
        }
        edges[ebase + 64 + l] = s;
    }
}

// ============ phase B: boundary slot unions ============
__global__ void bound_k(const int* __restrict__ edges, int* __restrict__ F) {
    int img = blockIdx.x / 248;
    int e = (blockIdx.x % 248) * 256 + threadIdx.x;
    int sA, sB;
    if (e < 31744) {            // vertical boundary: tx=k <-> k+1, row y
        int k = e >> 10, y = e & 1023;
        int ty = y >> 5, rr = y & 31;
        int tileA = img * 1024 + ty * 32 + k;
        sA = edges[tileA * 128 + 32 + rr];
        sB = edges[(tileA + 1) * 128 + rr];
    } else {                    // horizontal boundary
        int e2 = e - 31744;
        int k = e2 >> 10, x = e2 & 1023;
        int tileA = img * 1024 + k * 32 + (x >> 5);
        sA = edges[tileA * 128 + 96 + (x & 31)];
        sB = edges[(tileA + 32) * 128 + 64 + (x & 31)];
    }
    if (sA >= 0 && sB >= 0) unite_f(F, sA, sB);
}

// ============ phase C: fold donor fragments into final roots ============
__global__ void merge_frag_k(int* __restrict__ F, float* __restrict__ fragSums,
                             const int* __restrict__ fragCnt, int C) {
    int cidx = blockIdx.x;
    if (cidx >= C * 8) return;
    int cnt = fragCnt[cidx]; if (cnt > REGCAP) cnt = REGCAP;
    for (int off = threadIdx.x; off < cnt; off += 256) {
        int i = cidx * REGCAP + off;
        int rt = find_f(F, i);
        if (rt != i) {
            float2 d = ((const float2*)fragSums)[i];
            unsafeAtomicAdd(&fragSums[2 * rt], d.x);
            unsafeAtomicAdd(&fragSums[2 * rt + 1], d.y);
        }
    }
}

// ============ phase D: dice per region (one image per region), WRITE ======
__global__ void dice_frag_k(const int* __restrict__ F, const float2* __restrict__ fragSums,
                            const int* __restrict__ fragCnt,
                            float* __restrict__ partials, int b0, int C) {
    int cidx = blockIdx.x;
    if (cidx >= C * 8) return;
    int cnt = fragCnt[cidx]; if (cnt > REGCAP) cnt = REGCAP;
    float ds = 0.f, dn = 0.f;
    for (int off = threadIdx.x; off < cnt; off += 256) {
        int i = cidx * REGCAP + off;
        if (F[i] != i) continue;             // not a final root
        float2 s2 = fragSums[i];
        ds += (2.f * s2.x + 1e-6f) / (s2.y + 1e-6f);
        dn += 1.f;
    }
    #pragma unroll
    for (int d = 32; d > 0; d >>= 1) {
        ds += __shfl_down(ds, d);
        dn += __shfl_down(dn, d);
    }
    __shared__ float s_s[4], s_n[4];
    int wv = threadIdx.x >> 6;
    if ((threadIdx.x & 63) == 0) { s_s[wv] = ds; s_n[wv] = dn; }
    __syncthreads();
    if (threadIdx.x == 0) {
        int img = b0 + (cidx >> 3), sub = cidx & 7;
        partials[img * 16 + sub * 2]     = s_s[0] + s_s[1] + s_s[2] + s_s[3];
        partials[img * 16 + sub * 2 + 1] = s_n[0] + s_n[1] + s_n[2] + s_n[3];
    }
}

__global__ void zero_k(int* __restrict__ fragCnt) {
    if (threadIdx.x < NREG) fragCnt[threadIdx.x] = 0;
}

__global__ void final_k(const float* __restrict__ partials, float* __restrict__ out, int B) {
    if (threadIdx.x == 0 && blockIdx.x == 0) {
        float acc = 0.f;
        for (int img = 0; img < B; ++img) {
            float s = 0.f, n = 0.f;
            for (int sub = 0; sub < 8; ++sub) {
                s += partials[img * 16 + sub * 2];
                n += partials[img * 16 + sub * 2 + 1];
            }
            acc += (n > 0.f) ? (1.f - s / n) : 1.f;
        }
        out[0] = acc / (float)B;
    }
}

// ============ launch ============
extern "C" void kernel_launch(void* const* d_in, const int* in_sizes, int n_in,
                              void* d_out, int out_size, void* d_ws, size_t ws_size,
                              hipStream_t stream) {
    const float* pred = (const float*)d_in[0];
    const float* targ = (const float*)d_in[1];
    float* out = (float*)d_out;
    int B = in_sizes[0] / NPIX;
    if (B < 1) B = 1;

    char* ws = (char*)d_ws;
    size_t off = 0;
    float* partials = (float*)ws;                       // B*16 floats
    off += ((size_t)B * 16 * sizeof(float) + 255) & ~(size_t)255;
    int* fragCnt = (int*)(ws + off);
    off += ((size_t)NREG * 4 + 255) & ~(size_t)255;

    // fixed slot pool: F 1MB + fragSums 2MB
    const size_t NSLOT = (size_t)NREG * REGCAP;
    int*    F        = (int*)   (ws + off); off += NSLOT * 4;
    float2* fragSums = (float2*)(ws + off); off += NSLOT * 8;
    size_t fixed = off;

    const size_t perImg = (size_t)1024 * 128 * 4;       // edges only (512KB)
    int maxC = 1;
    if (ws_size > fixed + perImg) {
        size_t mm = (ws_size - fixed) / perImg;
        maxC = (int)(mm < (size_t)B ? mm : (size_t)B);
        if (maxC < 1) maxC = 1;
        if (maxC > 8) maxC = 8;
    }
    int* edgesA = (int*)(ws + off);

    for (int b0 = 0; b0 < B; b0 += maxC) {
        int C = (B - b0 < maxC) ? (B - b0) : maxC;
        const float* pc = pred + (size_t)b0 * NPIX;
        const float* tc = targ + (size_t)b0 * NPIX;
        int nwg = C * 256;
        zero_k<<<1, 64, 0, stream>>>(fragCnt);
        local_k<<<nwg, 256, 0, stream>>>((const float4*)pc, (const float4*)tc,
                                         edgesA, F, fragSums, fragCnt, nwg);
        bound_k<<<C * 248, 256, 0, stream>>>(edgesA, F);
        merge_frag_k<<<NREG, 256, 0, stream>>>(F, (float*)fragSums, fragCnt, C);
        dice_frag_k<<<NREG, 256, 0, stream>>>(F, fragSums, fragCnt, partials, b0, C);
    }

    final_k<<<1, 64, 0, stream>>>(partials, out, B);
}

// Round 13
// 96.148 us; speedup vs baseline: 1.7278x; 1.1700x over previous
//
#include <hip/hip_runtime.h>
#include <hip/hip_bf16.h>

#define NPIX (1 << 20)
#define HDIM 1024
#define NREG 64          // regions: img*8 + (tile&7)
#define REGCAP 4096      // slots per region

#define WBAR() __builtin_amdgcn_wave_barrier()

// ============ slot-level union-find (global, union-by-min) ============
__device__ __forceinline__ int find_f(int* F, int x) {
    for (;;) {
        int p = F[x];
        if (p == x) return x;
        int gp = F[p];
        if (gp == p) return p;
        F[x] = gp;   // path halving, benign race
        x = gp;
    }
}
__device__ __forceinline__ void unite_f(int* F, int a, int b) {
    a = find_f(F, a); b = find_f(F, b);
    while (a != b) {
        if (a < b) { int t = a; a = b; b = t; }
        int old = atomicCAS(&F[a], a, b);
        if (old == a) return;
        a = find_f(F, old); b = find_f(F, b);
    }
}

// ============ LDS union-find over run nodes (id = row*16 + k) ============
__device__ __forceinline__ int find_r(int* R, int n) {
    int p = R[n];
    while (p != n) {
        int gp = R[p];
        if (gp == p) return p;
        R[n] = gp;
        n = gp;
        p = R[n];
    }
    return n;
}
__device__ __forceinline__ void unite_r(int* R, int a, int b) {
    a = find_r(R, a); b = find_r(R, b);
    while (a != b) {
        if (a < b) { int t = a; a = b; b = t; }
        int old = atomicCAS(&R[a], a, b);
        if (old == a) return;
        a = find_r(R, old); b = find_r(R, b);
    }
}

// ============ phase A: 4 tiles/block, one tile per WAVE, interleaved ======
// (R10's proven version: serial find_r flatten + shuffle-scan slot rank)
__global__ __launch_bounds__(256) void local_k(
        const float4* __restrict__ pred4, const float4* __restrict__ targ4,
        int* __restrict__ edges, int* __restrict__ F,
        float2* __restrict__ fragSums,
        int* __restrict__ fragCnt, int nwg) {
    int wid = threadIdx.x >> 6;
    int l   = threadIdx.x & 63;
    int tile = wid * nwg + blockIdx.x;     // interleaved: block mixes 4 distant tiles
    int img = tile >> 10;
    int ty = (tile >> 5) & 31, tx = tile & 31;
    int r = l >> 1, h = l & 1;

    __shared__ int s_ruf[4][512];
    __shared__ float s_i[4][512], s_u[4][512];
    int*   ruf = &s_ruf[wid][0];
    float* si  = &s_i[wid][0];
    float* su  = &s_u[wid][0];

    int rowg = img * HDIM + ty * 32 + r;
    int qb = rowg * 256 + tx * 8 + h * 4;
    int ebase = tile * 128;

    float sv[16], iv[16];
    unsigned hm = 0;
    #pragma unroll
    for (int q = 0; q < 4; ++q) {
        float4 P4 = pred4[qb + q];
        float4 T4 = targ4[qb + q];
        float s0 = P4.x + T4.x, s1 = P4.y + T4.y, s2 = P4.z + T4.z, s3 = P4.w + T4.w;
        sv[q*4+0] = s0; sv[q*4+1] = s1; sv[q*4+2] = s2; sv[q*4+3] = s3;
        iv[q*4+0] = P4.x * T4.x; iv[q*4+1] = P4.y * T4.y;
        iv[q*4+2] = P4.z * T4.z; iv[q*4+3] = P4.w * T4.w;
        if (s0 > 0.f) hm |= 1u << (q*4+0);
        if (s1 > 0.f) hm |= 1u << (q*4+1);
        if (s2 > 0.f) hm |= 1u << (q*4+2);
        if (s3 > 0.f) hm |= 1u << (q*4+3);
    }
    unsigned m = hm << (h * 16);
    m |= __shfl_xor(m, 1);                 // full 32-bit row mask on both lanes
    unsigned st = m & ~(m << 1);           // run starts
    int nrun = __popc(st);

    if (__ballot(m != 0) == 0ull) {        // empty tile: -1 edges, 2 stores/lane
        edges[ebase + l] = -1;             // L(0..31) | R(32..63)
        edges[ebase + 64 + l] = -1;        // T(64..95) | B(96..127)
        return;
    }

    #pragma unroll
    for (int k = 0; k < 8; ++k) ruf[l * 8 + k] = l * 8 + k;

    // ---- P3a: per-run sums; straddler partial passed in registers ----
    int nrun0 = __popc(st & 0xFFFFu);
    bool strad = ((m >> 15) & 1) && ((m >> 16) & 1);
    float ai = 0.f, au = 0.f, fi = 0.f, fu = 0.f;
    int rid = h ? (nrun0 - 1) : -1;
    bool in = false;
    #pragma unroll
    for (int j = 0; j < 16; ++j) {
        if ((hm >> j) & 1) {
            int x = h * 16 + j;
            if ((st >> x) & 1) {
                if (in) { si[r*16+rid] = ai; su[r*16+rid] = au; }
                ++rid; ai = 0.f; au = 0.f; in = true;
            }
            if (in) { ai += iv[j]; au += sv[j]; }
            else    { fi += iv[j]; fu += sv[j]; }   // leading continuation (h=1)
        }
    }
    float gi = __shfl_xor(fi, 1), gu = __shfl_xor(fu, 1);
    if (in) {
        if (h == 0 && strad) { ai += gi; au += gu; }
        si[r*16+rid] = ai; su[r*16+rid] = au;
    }
    WBAR();
    // ---- P4: vertical run unions, lane pair per row boundary ----
    {
        int bsrc = (l & ~1) + 2; if (bsrc > 63) bsrc = 63;
        unsigned mb = __shfl(m, bsrc);
        if (l < 62) {
            unsigned stb = mb & ~(mb << 1);
            unsigned o = m & mb;
            unsigned os = o & ~(o << 1);
            os &= h ? 0xFFFF0000u : 0x0000FFFFu;
            while (os) {
                int x = __ffs(os) - 1; os &= os - 1;
                unsigned below = (2u << x) - 1;
                unite_r(ruf, r * 16 + __popc(st & below) - 1,
                             (r + 1) * 16 + __popc(stb & below) - 1);
            }
        }
    }
    WBAR();
    // ---- P5: flatten to depth<=1 + fold run sums into roots ----
    int root8[8]; bool valid8[8];
    #pragma unroll
    for (int k = 0; k < 8; ++k) {
        int ridx = k * 2 + h;
        int n = r * 16 + ridx;
        bool v = ridx < nrun;
        valid8[k] = v; root8[k] = n;
        if (v) {
            int root = find_r(ruf, n);
            root8[k] = root;
            if (root != n) {
                float a = si[n], b = su[n];
                ruf[n] = root;
                atomicAdd(&si[root], a);
                atomicAdd(&su[root], b);
            }
        }
    }
    WBAR();
    // ---- P7: slot alloc via distributed counter; region encodes image ----
    {
        bool isroot[8]; int mycnt = 0;
        #pragma unroll
        for (int k = 0; k < 8; ++k) {
            int n = r * 16 + k * 2 + h;
            bool rt = valid8[k] && (root8[k] == n);
            isroot[k] = rt; mycnt += rt;
        }
        int inc = mycnt;
        #pragma unroll
        for (int d = 1; d < 64; d <<= 1) {
            int t = __shfl_up(inc, d);
            if (l >= d) inc += t;
        }
        int cidx = (img << 3) | (tile & 7);
        int base = 0;
        if (l == 63) base = atomicAdd(&fragCnt[cidx], inc);
        base = __shfl(base, 63);
        int o = base + inc - mycnt;
        #pragma unroll
        for (int k = 0; k < 8; ++k) {
            if (isroot[k]) {
                int n = r * 16 + k * 2 + h;
                int off = o++;
                if (off < REGCAP) {
                    int slot = cidx * REGCAP + off;
                    F[slot] = slot;
                    fragSums[slot] = make_float2(si[n], su[n]);
                    ruf[n] = ~slot;
                } else ruf[n] = ~0;
            }
        }
    }
    WBAR();
    // ---- edges: L/R by row-pair, T/B one pixel per lane ----
    {
        int s = -1;
        if (h == 0) {
            if (m & 1u) { int v = ruf[r * 16]; s = (v < 0) ? ~v : ~ruf[v]; }
            edges[ebase + r] = s;
        } else {
            if (m >> 31) { int v = ruf[r * 16 + nrun - 1]; s = (v < 0) ? ~v : ~ruf[v]; }
            edges[ebase + 32 + r] = s;
        }
    }
    {
        int srcl = (l < 32) ? 0 : 62;      // lane holding full mask of row 0 / 31
        unsigned mm = __shfl(m, srcl);
        int x = l & 31;
        int s = -1;
        if ((mm >> x) & 1) {
            unsigned stt = mm & ~(mm << 1);
            int row = (l < 32) ? 0 : 31;
            int node = row * 16 + __popc(stt & ((2u << x) - 1)) - 1;
            int v = ruf[node];
            s = (v < 0) ? ~v : ~ruf[v];
        }
        edges[ebase + 64 + l] = s;
    }
}

// ============ phase B: boundary slot unions ============
__global__ void bound_k(const int* __restrict__ edges, int* __restrict__ F) {
    int img = blockIdx.x / 248;
    int e = (blockIdx.x % 248) * 256 + threadIdx.x;
    int sA, sB;
    if (e < 31744) {            // vertical boundary: tx=k <-> k+1, row y
        int k = e >> 10, y = e & 1023;
        int ty = y >> 5, rr = y & 31;
        int tileA = img * 1024 + ty * 32 + k;
        sA = edges[tileA * 128 + 32 + rr];
        sB = edges[(tileA + 1) * 128 + rr];
    } else {                    // horizontal boundary
        int e2 = e - 31744;
        int k = e2 >> 10, x = e2 & 1023;
        int tileA = img * 1024 + k * 32 + (x >> 5);
        sA = edges[tileA * 128 + 96 + (x & 31)];
        sB = edges[(tileA + 32) * 128 + 64 + (x & 31)];
    }
    if (sA >= 0 && sB >= 0) unite_f(F, sA, sB);
}

// ============ phase C: fold donors (4 sub-blocks per region = 256 blocks) ==
__global__ void merge_frag_k(int* __restrict__ F, float* __restrict__ fragSums,
                             const int* __restrict__ fragCnt, int C) {
    int cidx = blockIdx.x >> 2, sub = blockIdx.x & 3;
    if (cidx >= C * 8) return;
    int cnt = fragCnt[cidx]; if (cnt > REGCAP) cnt = REGCAP;
    int quarter = (cnt + 3) >> 2;
    int lo = sub * quarter;
    int hi = lo + quarter; if (hi > cnt) hi = cnt;
    for (int off = lo + threadIdx.x; off < hi; off += 256) {
        int i = cidx * REGCAP + off;
        int rt = find_f(F, i);
        if (rt != i) {
            float2 d = ((const float2*)fragSums)[i];
            unsafeAtomicAdd(&fragSums[2 * rt], d.x);
            unsafeAtomicAdd(&fragSums[2 * rt + 1], d.y);
        }
    }
}

// ============ phase D: dice (4 sub-blocks per region), WRITE partials ======
__global__ void dice_frag_k(const int* __restrict__ F, const float2* __restrict__ fragSums,
                            const int* __restrict__ fragCnt,
                            float* __restrict__ partials, int b0, int C) {
    int cidx = blockIdx.x >> 2, sub = blockIdx.x & 3;
    if (cidx >= C * 8) return;
    int cnt = fragCnt[cidx]; if (cnt > REGCAP) cnt = REGCAP;
    int quarter = (cnt + 3) >> 2;
    int lo = sub * quarter;
    int hi = lo + quarter; if (hi > cnt) hi = cnt;
    float ds = 0.f, dn = 0.f;
    for (int off = lo + threadIdx.x; off < hi; off += 256) {
        int i = cidx * REGCAP + off;
        if (F[i] != i) continue;             // not a final root
        float2 s2 = fragSums[i];
        ds += (2.f * s2.x + 1e-6f) / (s2.y + 1e-6f);
        dn += 1.f;
    }
    #pragma unroll
    for (int d = 32; d > 0; d >>= 1) {
        ds += __shfl_down(ds, d);
        dn += __shfl_down(dn, d);
    }
    __shared__ float s_s[4], s_n[4];
    int wv = threadIdx.x >> 6;
    if ((threadIdx.x & 63) == 0) { s_s[wv] = ds; s_n[wv] = dn; }
    __syncthreads();
    if (threadIdx.x == 0) {
        int img = b0 + (cidx >> 3);
        int slotp = ((cidx & 7) << 2) | sub;     // 32 partial pairs per image
        partials[img * 64 + slotp * 2]     = s_s[0] + s_s[1] + s_s[2] + s_s[3];
        partials[img * 64 + slotp * 2 + 1] = s_n[0] + s_n[1] + s_n[2] + s_n[3];
    }
}

__global__ void zero_k(int* __restrict__ fragCnt) {
    if (threadIdx.x < NREG) fragCnt[threadIdx.x] = 0;
}

__global__ void final_k(const float* __restrict__ partials, float* __restrict__ out, int B) {
    if (threadIdx.x == 0 && blockIdx.x == 0) {
        float acc = 0.f;
        for (int img = 0; img < B; ++img) {
            float s = 0.f, n = 0.f;
            for (int p = 0; p < 32; ++p) {
                s += partials[img * 64 + p * 2];
                n += partials[img * 64 + p * 2 + 1];
            }
            acc += (n > 0.f) ? (1.f - s / n) : 1.f;
        }
        out[0] = acc / (float)B;
    }
}

// ============ launch ============
extern "C" void kernel_launch(void* const* d_in, const int* in_sizes, int n_in,
                              void* d_out, int out_size, void* d_ws, size_t ws_size,
                              hipStream_t stream) {
    const float* pred = (const float*)d_in[0];
    const float* targ = (const float*)d_in[1];
    float* out = (float*)d_out;
    int B = in_sizes[0] / NPIX;
    if (B < 1) B = 1;

    char* ws = (char*)d_ws;
    size_t off = 0;
    float* partials = (float*)ws;                       // B*64 floats
    off += ((size_t)B * 64 * sizeof(float) + 255) & ~(size_t)255;
    int* fragCnt = (int*)(ws + off);
    off += ((size_t)NREG * 4 + 255) & ~(size_t)255;

    // fixed slot pool: F 1MB + fragSums 2MB
    const size_t NSLOT = (size_t)NREG * REGCAP;
    int*    F        = (int*)   (ws + off); off += NSLOT * 4;
    float2* fragSums = (float2*)(ws + off); off += NSLOT * 8;
    size_t fixed = off;

    const size_t perImg = (size_t)1024 * 128 * 4;       // edges only (512KB)
    int maxC = 1;
    if (ws_size > fixed + perImg) {
        size_t mm = (ws_size - fixed) / perImg;
        maxC = (int)(mm < (size_t)B ? mm : (size_t)B);
        if (maxC < 1) maxC = 1;
        if (maxC > 8) maxC = 8;
    }
    int* edgesA = (int*)(ws + off);

    for (int b0 = 0; b0 < B; b0 += maxC) {
        int C = (B - b0 < maxC) ? (B - b0) : maxC;
        const float* pc = pred + (size_t)b0 * NPIX;
        const float* tc = targ + (size_t)b0 * NPIX;
        int nwg = C * 256;
        zero_k<<<1, 64, 0, stream>>>(fragCnt);
        local_k<<<nwg, 256, 0, stream>>>((const float4*)pc, (const float4*)tc,
                                         edgesA, F, fragSums, fragCnt, nwg);
        bound_k<<<C * 248, 256, 0, stream>>>(edgesA, F);
        merge_frag_k<<<NREG * 4, 256, 0, stream>>>(F, (float*)fragSums, fragCnt, C);
        dice_frag_k<<<NREG * 4, 256, 0, stream>>>(F, fragSums, fragCnt, partials, b0, C);
    }

    final_k<<<1, 64, 0, stream>>>(partials, out, B);
}